// Round 1
// baseline (542.835 us; speedup 1.0000x reference)
//
#include <hip/hip_runtime.h>

#define B_ 8
#define T_ 2048
#define C_ 768
#define H_ 64
#define BT_ (B_*T_)

// ---------------- QKV projection: out[m] = x @ W[m], m in {q,k,v} --------------
// Block: 256 threads computes a 64-row x 64-col tile for one matrix.
// x staged transposed in LDS (xT[k][row]) so compute reads are float4.
constexpr int QKV_ROWS = 64;
constexpr int KC = 32;

__global__ __launch_bounds__(256) void qkv_kernel(
    const float* __restrict__ x, const float* __restrict__ Wq,
    const float* __restrict__ Wk, const float* __restrict__ Wv,
    float* __restrict__ qo, float* __restrict__ ko, float* __restrict__ vo)
{
    const int m = blockIdx.y;
    const int rowBase = blockIdx.x * QKV_ROWS;
    const float* __restrict__ W  = (m == 0) ? Wq : (m == 1) ? Wk : Wv;
    float* __restrict__ out      = (m == 0) ? qo : (m == 1) ? ko : vo;

    __shared__ float xT[KC][QKV_ROWS + 4];   // stride 68 words: f4-aligned, conflict-free reads
    __shared__ float wS[KC][H_ + 4];         // stride 68

    const int t  = threadIdx.x;
    const int rg = t >> 4;    // 0..15 -> rows rg*4..rg*4+3
    const int cg = t & 15;    // 0..15 -> cols cg*4..cg*4+3
    float acc[4][4] = {};

    for (int kc = 0; kc < C_; kc += KC) {
        __syncthreads();
        #pragma unroll
        for (int i = 0; i < 2; i++) {
            int f = t + 256 * i;                  // 0..511
            int row = f >> 3;                     // 8 float4 per row of 32 k
            int kk4 = (f & 7) << 2;
            float4 xv = *(const float4*)(x + (size_t)(rowBase + row) * C_ + kc + kk4);
            xT[kk4 + 0][row] = xv.x; xT[kk4 + 1][row] = xv.y;
            xT[kk4 + 2][row] = xv.z; xT[kk4 + 3][row] = xv.w;
        }
        #pragma unroll
        for (int i = 0; i < 2; i++) {
            int f = t + 256 * i;
            int kk = f >> 4;                      // 16 float4 per 64-col row
            int c4 = (f & 15) << 2;
            *(float4*)&wS[kk][c4] = *(const float4*)(W + (size_t)(kc + kk) * H_ + c4);
        }
        __syncthreads();
        #pragma unroll 8
        for (int kk = 0; kk < KC; kk++) {
            float4 a = *(const float4*)&xT[kk][rg << 2];
            float4 b = *(const float4*)&wS[kk][cg << 2];
            float av[4] = {a.x, a.y, a.z, a.w};
            float bv[4] = {b.x, b.y, b.z, b.w};
            #pragma unroll
            for (int i = 0; i < 4; i++)
                #pragma unroll
                for (int j = 0; j < 4; j++)
                    acc[i][j] += av[i] * bv[j];
        }
    }
    #pragma unroll
    for (int i = 0; i < 4; i++) {
        float4 o = make_float4(acc[i][0], acc[i][1], acc[i][2], acc[i][3]);
        *(float4*)(out + (size_t)(rowBase + (rg << 2) + i) * H_ + (cg << 2)) = o;
    }
}

// ---------------- Causal flash attention, fp32 vector ----------------
// One block per (batch, 32-row q tile). Online softmax matching reference:
// s = mask[b,q] * (q.k / sqrt(H)); s==0 -> -inf; k>q -> -inf; NaN rows -> 0.
constexpr int QT = 32;
constexpr int KT = 32;

__global__ __launch_bounds__(256) void attn_kernel(
    const float* __restrict__ q, const float* __restrict__ kM,
    const float* __restrict__ vM, const float* __restrict__ mask,
    float* __restrict__ out)
{
    const int bid = blockIdx.x;
    const int b   = bid >> 6;              // 64 q-tiles per batch
    const int qt  = 63 - (bid & 63);       // heavy tiles dispatched first
    const int qbase = qt * QT;

    __shared__ float qS[QT][H_ + 4];       // stride 68
    __shared__ float kS[KT][H_ + 4];
    __shared__ float vS[KT][H_ + 4];
    __shared__ float sS[QT][KT + 4];       // stride 36
    __shared__ float mrow[QT], lrow[QT], arow[QT];

    const int t  = threadIdx.x;
    const int r  = t >> 3;                 // q-row 0..31 (8 threads per row)
    const int c8 = t & 7;

    #pragma unroll
    for (int i = 0; i < 2; i++) {
        int f = t + 256 * i; int row = f >> 4; int c4 = (f & 15) << 2;
        *(float4*)&qS[row][c4] = *(const float4*)(q + ((size_t)b * T_ + qbase + row) * H_ + c4);
    }
    if (t < QT) { mrow[t] = -__builtin_inff(); lrow[t] = 0.f; }
    const float maskv = mask[(size_t)b * T_ + qbase + r];
    float O[8] = {};

    const int nkt = qt + 1;
    for (int kt = 0; kt < nkt; kt++) {
        __syncthreads();                   // protect kS/vS/sS from previous iter
        #pragma unroll
        for (int i = 0; i < 2; i++) {
            int f = t + 256 * i; int row = f >> 4; int c4 = (f & 15) << 2;
            size_t g = ((size_t)b * T_ + kt * KT + row) * H_ + c4;
            *(float4*)&kS[row][c4] = *(const float4*)(kM + g);
            *(float4*)&vS[row][c4] = *(const float4*)(vM + g);
        }
        __syncthreads();

        // S tile: thread computes row r, cols c8 + 8j
        float sv[4] = {};
        #pragma unroll 4
        for (int h = 0; h < H_; h += 4) {
            float4 qv = *(const float4*)&qS[r][h];
            #pragma unroll
            for (int j = 0; j < 4; j++) {
                float4 kv = *(const float4*)&kS[c8 + 8 * j][h];
                sv[j] += qv.x * kv.x + qv.y * kv.y + qv.z * kv.z + qv.w * kv.w;
            }
        }
        #pragma unroll
        for (int j = 0; j < 4; j++) {
            int kg = kt * KT + c8 + 8 * j;
            float s = sv[j] * 0.125f * maskv;
            if (s == 0.f) s = -__builtin_inff();
            if (kg > qbase + r) s = -__builtin_inff();
            sS[r][c8 + 8 * j] = s;
        }
        __syncthreads();

        // Online softmax update (one thread per row)
        if (t < QT) {
            float mold = mrow[t];
            float mx = mold;
            #pragma unroll 8
            for (int j2 = 0; j2 < KT; j2++) mx = fmaxf(mx, sS[t][j2]);
            float alpha, sum = 0.f;
            if (mx == -__builtin_inff()) {
                alpha = 1.f;
                #pragma unroll 8
                for (int j2 = 0; j2 < KT; j2++) sS[t][j2] = 0.f;
            } else {
                alpha = __expf(mold - mx);   // mold=-inf -> 0, correct
                #pragma unroll 8
                for (int j2 = 0; j2 < KT; j2++) {
                    float p = __expf(sS[t][j2] - mx);
                    sS[t][j2] = p;
                    sum += p;
                }
            }
            mrow[t] = mx;
            lrow[t] = lrow[t] * alpha + sum;
            arow[t] = alpha;
        }
        __syncthreads();

        // O = O*alpha + P @ V ; thread owns row r, cols c8*8 .. c8*8+7
        const float al = arow[r];
        #pragma unroll
        for (int jj = 0; jj < 8; jj++) O[jj] *= al;
        #pragma unroll 4
        for (int kk = 0; kk < KT; kk++) {
            float p = sS[r][kk];
            float4 v0 = *(const float4*)&vS[kk][c8 * 8];
            float4 v1 = *(const float4*)&vS[kk][c8 * 8 + 4];
            O[0] += p * v0.x; O[1] += p * v0.y; O[2] += p * v0.z; O[3] += p * v0.w;
            O[4] += p * v1.x; O[5] += p * v1.y; O[6] += p * v1.z; O[7] += p * v1.w;
        }
    }

    const float l = lrow[r];
    const float invl = (l > 0.f) ? 1.f / l : 0.f;   // NaN-row cleanup -> 0
    float4 o0 = make_float4(O[0] * invl, O[1] * invl, O[2] * invl, O[3] * invl);
    float4 o1 = make_float4(O[4] * invl, O[5] * invl, O[6] * invl, O[7] * invl);
    size_t g = ((size_t)b * T_ + qbase + r) * H_ + c8 * 8;
    *(float4*)(out + g)     = o0;
    *(float4*)(out + g + 4) = o1;
}

extern "C" void kernel_launch(void* const* d_in, const int* in_sizes, int n_in,
                              void* d_out, int out_size, void* d_ws, size_t ws_size,
                              hipStream_t stream) {
    const float* x    = (const float*)d_in[0];
    const float* mask = (const float*)d_in[1];
    const float* Wq   = (const float*)d_in[2];
    const float* Wk   = (const float*)d_in[3];
    const float* Wv   = (const float*)d_in[4];
    float* out = (float*)d_out;

    float* qw = (float*)d_ws;                  // [BT, H] fp32
    float* kw = qw + (size_t)BT_ * H_;
    float* vw = kw + (size_t)BT_ * H_;

    dim3 g1(BT_ / QKV_ROWS, 3);
    qkv_kernel<<<g1, 256, 0, stream>>>(x, Wq, Wk, Wv, qw, kw, vw);
    attn_kernel<<<B_ * (T_ / QT), 256, 0, stream>>>(qw, kw, vw, mask, out);
}

// Round 2
// 255.232 us; speedup vs baseline: 2.1268x; 2.1268x over previous
//
#include <hip/hip_runtime.h>
#include <hip/hip_bf16.h>

#define B_ 8
#define T_ 2048
#define C_ 768
#define H_ 64
#define BT_ (B_*T_)

typedef __attribute__((ext_vector_type(8))) short bf16x8;
typedef __attribute__((ext_vector_type(4))) float f32x4;

__device__ __forceinline__ unsigned short f2bf(float x) {
    __hip_bfloat16 h = __float2bfloat16(x);   // RNE
    return __builtin_bit_cast(unsigned short, h);
}

// ---------------- Fused QKV: q,k -> bf16 [B,T,H]; v -> bf16 transposed [B,H,T] ----
constexpr int RK = 32;

__global__ __launch_bounds__(256) void qkv_kernel(
    const float* __restrict__ x, const float* __restrict__ Wq,
    const float* __restrict__ Wk, const float* __restrict__ Wv,
    unsigned short* __restrict__ qo, unsigned short* __restrict__ ko,
    unsigned short* __restrict__ vTo)
{
    __shared__ __align__(16) float xT[RK][68];      // x transposed [k][row]
    __shared__ __align__(16) float wS[3][RK][68];
    const int t = threadIdx.x;
    const int rowBase = blockIdx.x * 64;
    const int rg = t >> 4, cg = t & 15;
    float acc[3][4][4] = {};

    for (int kc = 0; kc < C_; kc += RK) {
        __syncthreads();
        #pragma unroll
        for (int i = 0; i < 2; i++) {
            int f = t + 256 * i;
            int row = f >> 3;                    // 8 float4 per row of 32 k
            int k4 = (f & 7) << 2;
            float4 xv = *(const float4*)(x + (size_t)(rowBase + row) * C_ + kc + k4);
            xT[k4+0][row] = xv.x; xT[k4+1][row] = xv.y;
            xT[k4+2][row] = xv.z; xT[k4+3][row] = xv.w;
        }
        {
            const float* Ws[3] = {Wq, Wk, Wv};
            #pragma unroll
            for (int m = 0; m < 3; m++)
                #pragma unroll
                for (int i = 0; i < 2; i++) {
                    int f = t + 256 * i;
                    int kk = f >> 4;
                    int c4 = (f & 15) << 2;
                    *(float4*)&wS[m][kk][c4] = *(const float4*)(Ws[m] + (size_t)(kc + kk) * H_ + c4);
                }
        }
        __syncthreads();
        #pragma unroll 4
        for (int kk = 0; kk < RK; kk++) {
            float4 a = *(const float4*)&xT[kk][rg << 2];
            float av[4] = {a.x, a.y, a.z, a.w};
            #pragma unroll
            for (int m = 0; m < 3; m++) {
                float4 bb = *(const float4*)&wS[m][kk][cg << 2];
                float bv[4] = {bb.x, bb.y, bb.z, bb.w};
                #pragma unroll
                for (int i = 0; i < 4; i++)
                    #pragma unroll
                    for (int j = 0; j < 4; j++)
                        acc[m][i][j] += av[i] * bv[j];
            }
        }
    }

    const int b  = rowBase >> 11;
    const int t0 = rowBase & (T_ - 1);
    #pragma unroll
    for (int i = 0; i < 4; i++) {
        int row = rowBase + (rg << 2) + i;
        ushort4 uq, uk;
        uq.x = f2bf(acc[0][i][0]); uq.y = f2bf(acc[0][i][1]);
        uq.z = f2bf(acc[0][i][2]); uq.w = f2bf(acc[0][i][3]);
        uk.x = f2bf(acc[1][i][0]); uk.y = f2bf(acc[1][i][1]);
        uk.z = f2bf(acc[1][i][2]); uk.w = f2bf(acc[1][i][3]);
        *(ushort4*)(qo + (size_t)row * H_ + (cg << 2)) = uq;
        *(ushort4*)(ko + (size_t)row * H_ + (cg << 2)) = uk;
    }
    #pragma unroll
    for (int j = 0; j < 4; j++) {
        int h = (cg << 2) + j;
        ushort4 uv;
        uv.x = f2bf(acc[2][0][j]); uv.y = f2bf(acc[2][1][j]);
        uv.z = f2bf(acc[2][2][j]); uv.w = f2bf(acc[2][3][j]);
        *(ushort4*)(vTo + ((size_t)(b * H_) + h) * T_ + t0 + (rg << 2)) = uv;
    }
}

// ---------------- MFMA flash attention: 1 wave per 16-row q-tile -----------------
// S^T = K.Q^T  (C-layout: lane holds q=lane&15, k=quad*4+reg -> softmax mostly in-lane)
// P^T -> LDS [q][k] bf16 -> A/B frags ; O^T = V^T.P^T ; out[q][h] from C-layout.
__global__ __launch_bounds__(64) void attn_kernel(
    const unsigned short* __restrict__ qB, const unsigned short* __restrict__ kB,
    const unsigned short* __restrict__ vT, const float* __restrict__ mask,
    float* __restrict__ out)
{
    __shared__ __align__(16) unsigned short pS[16][88];  // row stride 176 B: 16B-aligned, 2-way banks (free)
    const int lane = threadIdx.x;
    const int q16  = lane & 15;
    const int quad = lane >> 4;
    const int bid  = blockIdx.x;
    const int b    = bid >> 7;
    const int qt   = 127 - (bid & 127);          // heavy tiles first
    const int qrow = (qt << 4) + q16;

    const size_t qoff = ((size_t)(b * T_) + qrow) * H_ + quad * 8;
    bf16x8 qf0 = *(const bf16x8*)(qB + qoff);
    bf16x8 qf1 = *(const bf16x8*)(qB + qoff + 32);
    const float maskv = mask[b * T_ + qrow] * 0.125f;    // fold 1/sqrt(64); pow2 scale exact

    f32x4 o[4] = {};
    float m_run = -__builtin_inff();
    float l_run = 0.f;

    const int niter = ((qt << 4) + 16 + 63) >> 6;
    for (int kt = 0; kt < niter; kt++) {
        const int kbase = kt << 6;

        // ---- S^T tiles: D[k_local][q] over 64 k
        f32x4 sa[4] = {};
        #pragma unroll
        for (int sub = 0; sub < 4; sub++) {
            const unsigned short* kp = kB + ((size_t)(b * T_) + kbase + sub * 16 + q16) * H_ + quad * 8;
            bf16x8 kf0 = *(const bf16x8*)(kp);
            bf16x8 kf1 = *(const bf16x8*)(kp + 32);
            sa[sub] = __builtin_amdgcn_mfma_f32_16x16x32_bf16(kf0, qf0, sa[sub], 0, 0, 0);
            sa[sub] = __builtin_amdgcn_mfma_f32_16x16x32_bf16(kf1, qf1, sa[sub], 0, 0, 0);
        }

        // ---- reference semantics: s = mask*qk/8 ; s==0 -> -inf ; causal -> -inf
        float s[16];
        #pragma unroll
        for (int sub = 0; sub < 4; sub++)
            #pragma unroll
            for (int r = 0; r < 4; r++) {
                int kidx = kbase + sub * 16 + quad * 4 + r;
                float sv = sa[sub][r] * maskv;
                sv = (sv == 0.f) ? -__builtin_inff() : sv;
                sv = (kidx > qrow) ? -__builtin_inff() : sv;
                s[sub * 4 + r] = sv;
            }

        // ---- online softmax (per lane: one q-row; reduce in-lane + xor 16/32)
        float mx = s[0];
        #pragma unroll
        for (int i = 1; i < 16; i++) mx = fmaxf(mx, s[i]);
        mx = fmaxf(mx, __shfl_xor(mx, 16));
        mx = fmaxf(mx, __shfl_xor(mx, 32));
        float m_new = fmaxf(m_run, mx);
        float m_use = (m_new == -__builtin_inff()) ? 0.f : m_new;  // dead row: avoid inf-inf
        float alpha = __expf(m_run - m_use);                        // m_run=-inf -> 0
        float p[16], psum = 0.f;
        #pragma unroll
        for (int i = 0; i < 16; i++) { p[i] = __expf(s[i] - m_use); psum += p[i]; }
        psum += __shfl_xor(psum, 16);
        psum += __shfl_xor(psum, 32);
        l_run = l_run * alpha + psum;
        m_run = m_new;
        #pragma unroll
        for (int ht = 0; ht < 4; ht++)
            #pragma unroll
            for (int r = 0; r < 4; r++) o[ht][r] *= alpha;

        // ---- P^T -> LDS as P[q][k] bf16 (4x ds_write_b64, 2-way banks)
        #pragma unroll
        for (int sub = 0; sub < 4; sub++) {
            unsigned int lo = (unsigned int)f2bf(p[sub * 4 + 0]) | ((unsigned int)f2bf(p[sub * 4 + 1]) << 16);
            unsigned int hi = (unsigned int)f2bf(p[sub * 4 + 2]) | ((unsigned int)f2bf(p[sub * 4 + 3]) << 16);
            *(uint2*)&pS[q16][sub * 16 + quad * 4] = make_uint2(lo, hi);
        }
        __syncthreads();   // single-wave block: cheap, orders LDS write->read

        bf16x8 pf0 = *(const bf16x8*)&pS[q16][quad * 8];
        bf16x8 pf1 = *(const bf16x8*)&pS[q16][32 + quad * 8];
        #pragma unroll
        for (int ht = 0; ht < 4; ht++) {
            const unsigned short* vp = vT + ((size_t)(b * H_) + ht * 16 + q16) * T_ + kbase + quad * 8;
            bf16x8 vf0 = *(const bf16x8*)(vp);
            bf16x8 vf1 = *(const bf16x8*)(vp + 32);
            o[ht] = __builtin_amdgcn_mfma_f32_16x16x32_bf16(vf0, pf0, o[ht], 0, 0, 0);
            o[ht] = __builtin_amdgcn_mfma_f32_16x16x32_bf16(vf1, pf1, o[ht], 0, 0, 0);
        }
        __syncthreads();   // protect pS before next iteration's writes
    }

    const float invl = (l_run > 0.f) ? (1.f / l_run) : 0.f;  // fully-masked row -> 0
    #pragma unroll
    for (int ht = 0; ht < 4; ht++) {
        float4 ov = make_float4(o[ht][0] * invl, o[ht][1] * invl, o[ht][2] * invl, o[ht][3] * invl);
        *(float4*)(out + ((size_t)(b * T_) + qrow) * H_ + ht * 16 + quad * 4) = ov;
    }
}

extern "C" void kernel_launch(void* const* d_in, const int* in_sizes, int n_in,
                              void* d_out, int out_size, void* d_ws, size_t ws_size,
                              hipStream_t stream) {
    const float* x    = (const float*)d_in[0];
    const float* mask = (const float*)d_in[1];
    const float* Wq   = (const float*)d_in[2];
    const float* Wk   = (const float*)d_in[3];
    const float* Wv   = (const float*)d_in[4];
    float* out = (float*)d_out;

    unsigned short* qw = (unsigned short*)d_ws;            // bf16 [B,T,H]
    unsigned short* kw = qw + (size_t)BT_ * H_;            // bf16 [B,T,H]
    unsigned short* vw = kw + (size_t)BT_ * H_;            // bf16 [B,H,T]

    qkv_kernel<<<BT_ / 64, 256, 0, stream>>>(x, Wq, Wk, Wv, qw, kw, vw);
    attn_kernel<<<B_ * (T_ / 16), 64, 0, stream>>>(qw, kw, vw, mask, out);
}

// Round 3
// 195.846 us; speedup vs baseline: 2.7717x; 1.3032x over previous
//
#include <hip/hip_runtime.h>
#include <hip/hip_bf16.h>

#define B_ 8
#define T_ 2048
#define C_ 768
#define H_ 64
#define BT_ (B_*T_)

typedef __attribute__((ext_vector_type(8))) short bf16x8;
typedef __attribute__((ext_vector_type(4))) float f32x4;

__device__ __forceinline__ unsigned short f2bf(float x) {
    __hip_bfloat16 h = __float2bfloat16(x);   // RNE
    return __builtin_bit_cast(unsigned short, h);
}

__device__ __forceinline__ bf16x8 cvt8(float4 a, float4 b) {
    bf16x8 r;
    r[0] = (short)f2bf(a.x); r[1] = (short)f2bf(a.y);
    r[2] = (short)f2bf(a.z); r[3] = (short)f2bf(a.w);
    r[4] = (short)f2bf(b.x); r[5] = (short)f2bf(b.y);
    r[6] = (short)f2bf(b.z); r[7] = (short)f2bf(b.w);
    return r;
}

// ---------------- W prep: WT[j=m*64+n][k] = bf16(W_m[k][n]), j in [0,192) -------
__global__ __launch_bounds__(256) void wprep(
    const float* __restrict__ Wq, const float* __restrict__ Wk,
    const float* __restrict__ Wv, unsigned short* __restrict__ WT)
{
    const int j = blockIdx.x;            // 0..191
    const int m = j >> 6, n = j & 63;
    const float* __restrict__ W = (m == 0) ? Wq : (m == 1) ? Wk : Wv;
    for (int k = threadIdx.x; k < C_; k += 256)
        WT[(size_t)j * C_ + k] = f2bf(W[(size_t)k * H_ + n]);
}

// ---------------- QKV via MFMA: one wave per 16 token rows, all 192 cols --------
// D = WT_rows x x_rows -> D[n][token]: col=lane&15=token, row=quad*4+reg=n_local.
__global__ __launch_bounds__(64) void qkv_kernel(
    const float* __restrict__ x, const unsigned short* __restrict__ WT,
    unsigned short* __restrict__ qo, unsigned short* __restrict__ ko,
    unsigned short* __restrict__ vTo)
{
    const int lane = threadIdx.x;
    const int q16 = lane & 15, quad = lane >> 4;
    const int rowBase = blockIdx.x << 4;
    const int row = rowBase + q16;
    const int b = rowBase >> 11, t0 = rowBase & (T_ - 1);

    f32x4 acc[12] = {};
    const float* __restrict__ xp = x + (size_t)row * C_ + quad * 8;

    #pragma unroll 2
    for (int kk = 0; kk < C_; kk += 32) {
        float4 xa = *(const float4*)(xp + kk);
        float4 xb = *(const float4*)(xp + kk + 4);
        bf16x8 xf = cvt8(xa, xb);
        const unsigned short* wp = WT + (size_t)q16 * C_ + kk + quad * 8;
        #pragma unroll
        for (int f = 0; f < 12; f++) {
            bf16x8 wf = *(const bf16x8*)(wp + (size_t)(f * 16) * C_);
            acc[f] = __builtin_amdgcn_mfma_f32_16x16x32_bf16(wf, xf, acc[f], 0, 0, 0);
        }
    }

    // q, k: [B,T,H] bf16 — lane holds token=row, 4 consecutive n per frag
    #pragma unroll
    for (int f = 0; f < 8; f++) {
        ushort4 u;
        u.x = f2bf(acc[f][0]); u.y = f2bf(acc[f][1]);
        u.z = f2bf(acc[f][2]); u.w = f2bf(acc[f][3]);
        unsigned short* __restrict__ dst = (f < 4) ? qo : ko;
        *(ushort4*)(dst + (size_t)row * H_ + (f & 3) * 16 + quad * 4) = u;
    }
    // v: transposed [B,H,T] bf16
    #pragma unroll
    for (int f = 8; f < 12; f++)
        #pragma unroll
        for (int r = 0; r < 4; r++) {
            int h = (f - 8) * 16 + quad * 4 + r;
            vTo[((size_t)(b * H_) + h) * T_ + t0 + q16] = f2bf(acc[f][r]);
        }
}

// ---------------- MFMA flash attention: 2 waves/block, k-tiles interleaved ------
__global__ __launch_bounds__(128) void attn_kernel(
    const unsigned short* __restrict__ qB, const unsigned short* __restrict__ kB,
    const unsigned short* __restrict__ vT, const float* __restrict__ mask,
    float* __restrict__ out)
{
    __shared__ __align__(16) unsigned short pS[2][16][88];  // per-wave P tile
    __shared__ float oS[64][17];
    __shared__ float mS[64], lS[64];

    const int tid  = threadIdx.x;
    const int w    = tid >> 6;
    const int lane = tid & 63;
    const int q16  = lane & 15;
    const int quad = lane >> 4;
    const int bid  = blockIdx.x;
    const int b    = bid >> 7;
    const int qt   = 127 - (bid & 127);          // heavy tiles first
    const int qrow = (qt << 4) + q16;

    const size_t qoff = ((size_t)(b * T_) + qrow) * H_ + quad * 8;
    bf16x8 qf0 = *(const bf16x8*)(qB + qoff);
    bf16x8 qf1 = *(const bf16x8*)(qB + qoff + 32);
    const float maskv = mask[b * T_ + qrow] * 0.125f;   // fold 1/sqrt(64)

    f32x4 o[4] = {};
    float m_run = -__builtin_inff();
    float l_run = 0.f;

    const int niter = ((qt << 4) + 16 + 63) >> 6;   // 64-wide k tiles
    const int nhalf = (niter + 1) >> 1;             // per-wave iterations (equal!)
    for (int i = 0; i < nhalf; i++) {
        const int  kt     = 2 * i + w;
        const bool active = (kt < niter);
        const int  kbase  = (active ? kt : 0) << 6;

        // ---- S^T tiles: D[k_local][q] over 64 k
        f32x4 sa[4] = {};
        #pragma unroll
        for (int sub = 0; sub < 4; sub++) {
            const unsigned short* kp = kB + ((size_t)(b * T_) + kbase + sub * 16 + q16) * H_ + quad * 8;
            bf16x8 kf0 = *(const bf16x8*)(kp);
            bf16x8 kf1 = *(const bf16x8*)(kp + 32);
            sa[sub] = __builtin_amdgcn_mfma_f32_16x16x32_bf16(kf0, qf0, sa[sub], 0, 0, 0);
            sa[sub] = __builtin_amdgcn_mfma_f32_16x16x32_bf16(kf1, qf1, sa[sub], 0, 0, 0);
        }

        // ---- reference semantics: s = mask*qk/8 ; s==0 -> -inf ; causal -> -inf
        float s[16];
        #pragma unroll
        for (int sub = 0; sub < 4; sub++)
            #pragma unroll
            for (int r = 0; r < 4; r++) {
                int kidx = kbase + sub * 16 + quad * 4 + r;
                float sv = sa[sub][r] * maskv;
                sv = (sv == 0.f) ? -__builtin_inff() : sv;
                sv = (kidx > qrow || !active) ? -__builtin_inff() : sv;
                s[sub * 4 + r] = sv;
            }

        // ---- online softmax (lane owns one q-row slice; xor 16/32 reduce)
        float mx = s[0];
        #pragma unroll
        for (int i2 = 1; i2 < 16; i2++) mx = fmaxf(mx, s[i2]);
        mx = fmaxf(mx, __shfl_xor(mx, 16));
        mx = fmaxf(mx, __shfl_xor(mx, 32));
        float m_new = fmaxf(m_run, mx);
        float m_use = (m_new == -__builtin_inff()) ? 0.f : m_new;
        float alpha = __expf(m_run - m_use);
        float p[16], psum = 0.f;
        #pragma unroll
        for (int i2 = 0; i2 < 16; i2++) { p[i2] = __expf(s[i2] - m_use); psum += p[i2]; }
        psum += __shfl_xor(psum, 16);
        psum += __shfl_xor(psum, 32);
        l_run = l_run * alpha + psum;
        m_run = m_new;
        #pragma unroll
        for (int ht = 0; ht < 4; ht++)
            #pragma unroll
            for (int r = 0; r < 4; r++) o[ht][r] *= alpha;

        // ---- P^T -> LDS as P[q][k] bf16
        #pragma unroll
        for (int sub = 0; sub < 4; sub++) {
            unsigned int lo = (unsigned int)f2bf(p[sub * 4 + 0]) | ((unsigned int)f2bf(p[sub * 4 + 1]) << 16);
            unsigned int hi = (unsigned int)f2bf(p[sub * 4 + 2]) | ((unsigned int)f2bf(p[sub * 4 + 3]) << 16);
            *(uint2*)&pS[w][q16][sub * 16 + quad * 4] = make_uint2(lo, hi);
        }
        __syncthreads();     // equal trip counts on both waves

        bf16x8 pf0 = *(const bf16x8*)&pS[w][q16][quad * 8];
        bf16x8 pf1 = *(const bf16x8*)&pS[w][q16][32 + quad * 8];
        #pragma unroll
        for (int ht = 0; ht < 4; ht++) {
            const unsigned short* vp = vT + ((size_t)(b * H_) + ht * 16 + q16) * T_ + kbase + quad * 8;
            bf16x8 vf0 = *(const bf16x8*)(vp);
            bf16x8 vf1 = *(const bf16x8*)(vp + 32);
            o[ht] = __builtin_amdgcn_mfma_f32_16x16x32_bf16(vf0, pf0, o[ht], 0, 0, 0);
            o[ht] = __builtin_amdgcn_mfma_f32_16x16x32_bf16(vf1, pf1, o[ht], 0, 0, 0);
        }
        __syncthreads();
    }

    // ---- merge the two waves' online-softmax states
    if (w == 1) {
        mS[lane] = m_run; lS[lane] = l_run;
        #pragma unroll
        for (int ht = 0; ht < 4; ht++)
            #pragma unroll
            for (int r = 0; r < 4; r++) oS[lane][ht * 4 + r] = o[ht][r];
    }
    __syncthreads();
    if (w == 0) {
        float m1 = mS[lane], l1 = lS[lane];
        float m  = fmaxf(m_run, m1);
        float mu = (m == -__builtin_inff()) ? 0.f : m;
        float a0 = __expf(m_run - mu), a1 = __expf(m1 - mu);
        float l  = l_run * a0 + l1 * a1;
        float invl = (l > 0.f) ? (1.f / l) : 0.f;   // fully-masked row -> 0
        #pragma unroll
        for (int ht = 0; ht < 4; ht++) {
            float4 ov;
            ov.x = (o[ht][0] * a0 + oS[lane][ht * 4 + 0] * a1) * invl;
            ov.y = (o[ht][1] * a0 + oS[lane][ht * 4 + 1] * a1) * invl;
            ov.z = (o[ht][2] * a0 + oS[lane][ht * 4 + 2] * a1) * invl;
            ov.w = (o[ht][3] * a0 + oS[lane][ht * 4 + 3] * a1) * invl;
            *(float4*)(out + ((size_t)(b * T_) + qrow) * H_ + ht * 16 + quad * 4) = ov;
        }
    }
}

extern "C" void kernel_launch(void* const* d_in, const int* in_sizes, int n_in,
                              void* d_out, int out_size, void* d_ws, size_t ws_size,
                              hipStream_t stream) {
    const float* x    = (const float*)d_in[0];
    const float* mask = (const float*)d_in[1];
    const float* Wq   = (const float*)d_in[2];
    const float* Wk   = (const float*)d_in[3];
    const float* Wv   = (const float*)d_in[4];
    float* out = (float*)d_out;

    unsigned short* qw = (unsigned short*)d_ws;            // bf16 [B,T,H]
    unsigned short* kw = qw + (size_t)BT_ * H_;            // bf16 [B,T,H]
    unsigned short* vw = kw + (size_t)BT_ * H_;            // bf16 [B,H,T]
    unsigned short* wt = vw + (size_t)BT_ * H_;            // bf16 [192][768]

    wprep<<<192, 256, 0, stream>>>(Wq, Wk, Wv, wt);
    qkv_kernel<<<BT_ / 16, 64, 0, stream>>>(x, wt, qw, kw, vw);
    attn_kernel<<<B_ * (T_ / 16), 128, 0, stream>>>(qw, kw, vw, mask, out);
}

// Round 4
// 171.164 us; speedup vs baseline: 3.1714x; 1.1442x over previous
//
#include <hip/hip_runtime.h>
#include <hip/hip_bf16.h>

#define B_ 8
#define T_ 2048
#define C_ 768
#define H_ 64
#define BT_ (B_*T_)

typedef __attribute__((ext_vector_type(8))) short bf16x8;
typedef __attribute__((ext_vector_type(4))) float f32x4;

__device__ __forceinline__ unsigned short f2bf(float x) {
    __hip_bfloat16 h = __float2bfloat16(x);   // RNE
    return __builtin_bit_cast(unsigned short, h);
}

__device__ __forceinline__ bf16x8 cvt8(float4 a, float4 b) {
    bf16x8 r;
    r[0] = (short)f2bf(a.x); r[1] = (short)f2bf(a.y);
    r[2] = (short)f2bf(a.z); r[3] = (short)f2bf(a.w);
    r[4] = (short)f2bf(b.x); r[5] = (short)f2bf(b.y);
    r[6] = (short)f2bf(b.z); r[7] = (short)f2bf(b.w);
    return r;
}

// ------------- W prep (coalesced LDS transpose): WT[m*64+n][k] = bf16(W_m[k][n])
__global__ __launch_bounds__(256) void wprep(
    const float* __restrict__ Wq, const float* __restrict__ Wk,
    const float* __restrict__ Wv, unsigned short* __restrict__ WT)
{
    __shared__ float tile[64][65];
    const int bidx = blockIdx.x;             // 36 = 3 m * 12 k-tiles
    const int m = bidx / 12, kt = bidx % 12;
    const float* __restrict__ W = (m == 0) ? Wq : (m == 1) ? Wk : Wv;
    const int t = threadIdx.x;
    const int n = t & 63, kr = t >> 6;
    #pragma unroll
    for (int r = kr; r < 64; r += 4)
        tile[r][n] = W[(size_t)(kt * 64 + r) * H_ + n];   // coalesced 256B rows
    __syncthreads();
    const int n2 = t >> 2, k0 = (t & 3) * 16;
    #pragma unroll
    for (int g = 0; g < 4; g++) {
        ushort4 u;
        u.x = f2bf(tile[k0 + g * 4 + 0][n2]);
        u.y = f2bf(tile[k0 + g * 4 + 1][n2]);
        u.z = f2bf(tile[k0 + g * 4 + 2][n2]);
        u.w = f2bf(tile[k0 + g * 4 + 3][n2]);
        *(ushort4*)(WT + (size_t)(m * 64 + n2) * C_ + kt * 64 + k0 + g * 4) = u;
    }
}

// ------------- QKV via MFMA: 2 waves/block (C-split), 16 tokens/block ----------
__global__ __launch_bounds__(128) void qkv_kernel(
    const float* __restrict__ x, const unsigned short* __restrict__ WT,
    unsigned short* __restrict__ qo, unsigned short* __restrict__ ko,
    unsigned short* __restrict__ vTo)
{
    __shared__ float accS[64][49];
    const int tid = threadIdx.x;
    const int w = tid >> 6, lane = tid & 63;
    const int q16 = lane & 15, quad = lane >> 4;
    const int rowBase = blockIdx.x << 4;
    const int row = rowBase + q16;
    const int b = rowBase >> 11, t0 = rowBase & (T_ - 1);

    f32x4 acc[12] = {};
    const float* __restrict__ xp = x + (size_t)row * C_ + w * 384 + quad * 8;
    const unsigned short* __restrict__ wbase = WT + (size_t)q16 * C_ + w * 384 + quad * 8;

    #pragma unroll 2
    for (int kk = 0; kk < 384; kk += 32) {
        float4 xa = *(const float4*)(xp + kk);
        float4 xb = *(const float4*)(xp + kk + 4);
        bf16x8 xf = cvt8(xa, xb);
        const unsigned short* wp = wbase + kk;
        #pragma unroll
        for (int f = 0; f < 12; f++) {
            bf16x8 wf = *(const bf16x8*)(wp + (size_t)(f * 16) * C_);
            acc[f] = __builtin_amdgcn_mfma_f32_16x16x32_bf16(wf, xf, acc[f], 0, 0, 0);
        }
    }

    if (w == 1) {
        #pragma unroll
        for (int f = 0; f < 12; f++)
            #pragma unroll
            for (int r = 0; r < 4; r++) accS[lane][f * 4 + r] = acc[f][r];
    }
    __syncthreads();
    if (w == 0) {
        #pragma unroll
        for (int f = 0; f < 12; f++)
            #pragma unroll
            for (int r = 0; r < 4; r++) acc[f][r] += accS[lane][f * 4 + r];

        #pragma unroll
        for (int f = 0; f < 8; f++) {
            ushort4 u;
            u.x = f2bf(acc[f][0]); u.y = f2bf(acc[f][1]);
            u.z = f2bf(acc[f][2]); u.w = f2bf(acc[f][3]);
            unsigned short* __restrict__ dst = (f < 4) ? qo : ko;
            *(ushort4*)(dst + (size_t)row * H_ + (f & 3) * 16 + quad * 4) = u;
        }
        #pragma unroll
        for (int f = 8; f < 12; f++)
            #pragma unroll
            for (int r = 0; r < 4; r++) {
                int h = (f - 8) * 16 + quad * 4 + r;
                vTo[((size_t)(b * H_) + h) * T_ + t0 + q16] = f2bf(acc[f][r]);
            }
    }
}

// ------------- MFMA flash attention: 4 waves/block k-split, NO in-loop barriers -
__global__ __launch_bounds__(256) void attn_kernel(
    const unsigned short* __restrict__ qB, const unsigned short* __restrict__ kB,
    const unsigned short* __restrict__ vT, const float* __restrict__ mask,
    float* __restrict__ out)
{
    __shared__ __align__(16) unsigned short pS[4][16][88];  // wave-private P tiles
    __shared__ float oS[3][64][17];
    __shared__ float mlS[3][64][2];

    const int tid  = threadIdx.x;
    const int w    = tid >> 6;
    const int lane = tid & 63;
    const int q16  = lane & 15;
    const int quad = lane >> 4;
    const int bid  = blockIdx.x;
    const int b    = bid & 7;                    // batches interleaved
    const int qt   = 127 - (bid >> 3);           // heavy q-tiles first
    const int qrow = (qt << 4) + q16;

    const size_t qoff = ((size_t)(b * T_) + qrow) * H_ + quad * 8;
    bf16x8 qf0 = *(const bf16x8*)(qB + qoff);
    bf16x8 qf1 = *(const bf16x8*)(qB + qoff + 32);
    // fold 1/sqrt(64) and log2(e): softmax runs in base-2 domain
    const float maskv = mask[b * T_ + qrow] * 0.125f * 1.44269504f;

    f32x4 o[4] = {};
    float m_run = -__builtin_inff();
    float l_run = 0.f;

    const int niter = ((qt << 4) + 16 + 63) >> 6;   // 64-wide k tiles
    for (int kt = w; kt < niter; kt += 4) {
        const int kbase = kt << 6;

        // ---- K and V fragment loads (issued together; V covers softmax latency)
        bf16x8 kf[8], vf[8];
        #pragma unroll
        for (int sub = 0; sub < 4; sub++) {
            const unsigned short* kp = kB + ((size_t)(b * T_) + kbase + sub * 16 + q16) * H_ + quad * 8;
            kf[2 * sub]     = *(const bf16x8*)(kp);
            kf[2 * sub + 1] = *(const bf16x8*)(kp + 32);
        }
        #pragma unroll
        for (int ht = 0; ht < 4; ht++) {
            const unsigned short* vp = vT + ((size_t)(b * H_) + ht * 16 + q16) * T_ + kbase + quad * 8;
            vf[2 * ht]     = *(const bf16x8*)(vp);
            vf[2 * ht + 1] = *(const bf16x8*)(vp + 32);
        }

        // ---- S^T = K.Q^T : D[k_local][q]
        f32x4 sa[4] = {};
        #pragma unroll
        for (int sub = 0; sub < 4; sub++) {
            sa[sub] = __builtin_amdgcn_mfma_f32_16x16x32_bf16(kf[2 * sub],     qf0, sa[sub], 0, 0, 0);
            sa[sub] = __builtin_amdgcn_mfma_f32_16x16x32_bf16(kf[2 * sub + 1], qf1, sa[sub], 0, 0, 0);
        }

        // ---- reference semantics: s = mask*qk/8 (log2 dom); s==0 -> -inf; causal
        float s[16];
        #pragma unroll
        for (int sub = 0; sub < 4; sub++)
            #pragma unroll
            for (int r = 0; r < 4; r++) {
                int kidx = kbase + sub * 16 + quad * 4 + r;
                float sv = sa[sub][r] * maskv;
                sv = (sv == 0.f) ? -__builtin_inff() : sv;
                sv = (kidx > qrow) ? -__builtin_inff() : sv;
                s[sub * 4 + r] = sv;
            }

        // ---- online softmax (base-2). xor-16/32 reduce across the 4 lane-quads.
        float mx = s[0];
        #pragma unroll
        for (int i2 = 1; i2 < 16; i2++) mx = fmaxf(mx, s[i2]);
        mx = fmaxf(mx, __shfl_xor(mx, 16));
        mx = fmaxf(mx, __shfl_xor(mx, 32));
        float m_new = fmaxf(m_run, mx);
        float m_use = (m_new == -__builtin_inff()) ? 0.f : m_new;
        float alpha = exp2f(m_run - m_use);
        float p[16], psum = 0.f;
        #pragma unroll
        for (int i2 = 0; i2 < 16; i2++) { p[i2] = exp2f(s[i2] - m_use); psum += p[i2]; }
        psum += __shfl_xor(psum, 16);
        psum += __shfl_xor(psum, 32);
        l_run = l_run * alpha + psum;
        m_run = m_new;
        #pragma unroll
        for (int ht = 0; ht < 4; ht++)
            #pragma unroll
            for (int r = 0; r < 4; r++) o[ht][r] *= alpha;

        // ---- P^T -> wave-private LDS as P[q][k] bf16 (intra-wave: no barrier)
        #pragma unroll
        for (int sub = 0; sub < 4; sub++) {
            unsigned int lo = (unsigned int)f2bf(p[sub * 4 + 0]) | ((unsigned int)f2bf(p[sub * 4 + 1]) << 16);
            unsigned int hi = (unsigned int)f2bf(p[sub * 4 + 2]) | ((unsigned int)f2bf(p[sub * 4 + 3]) << 16);
            *(uint2*)&pS[w][q16][sub * 16 + quad * 4] = make_uint2(lo, hi);
        }
        bf16x8 pf0 = *(const bf16x8*)&pS[w][q16][quad * 8];
        bf16x8 pf1 = *(const bf16x8*)&pS[w][q16][32 + quad * 8];

        // ---- O^T += V^T.P^T
        #pragma unroll
        for (int ht = 0; ht < 4; ht++) {
            o[ht] = __builtin_amdgcn_mfma_f32_16x16x32_bf16(vf[2 * ht],     pf0, o[ht], 0, 0, 0);
            o[ht] = __builtin_amdgcn_mfma_f32_16x16x32_bf16(vf[2 * ht + 1], pf1, o[ht], 0, 0, 0);
        }
    }

    // ---- merge the 4 waves' online-softmax states
    if (w > 0) {
        mlS[w - 1][lane][0] = m_run;
        mlS[w - 1][lane][1] = l_run;
        #pragma unroll
        for (int ht = 0; ht < 4; ht++)
            #pragma unroll
            for (int r = 0; r < 4; r++) oS[w - 1][lane][ht * 4 + r] = o[ht][r];
    }
    __syncthreads();
    if (w == 0) {
        float mm[3], ll[3];
        float m = m_run;
        #pragma unroll
        for (int j = 0; j < 3; j++) {
            mm[j] = mlS[j][lane][0]; ll[j] = mlS[j][lane][1];
            m = fmaxf(m, mm[j]);
        }
        float mu = (m == -__builtin_inff()) ? 0.f : m;
        float a0 = exp2f(m_run - mu);
        float aj[3];
        float l = l_run * a0;
        #pragma unroll
        for (int j = 0; j < 3; j++) { aj[j] = exp2f(mm[j] - mu); l += ll[j] * aj[j]; }
        float invl = (l > 0.f) ? (1.f / l) : 0.f;   // fully-masked row -> 0
        #pragma unroll
        for (int ht = 0; ht < 4; ht++) {
            float4 ov;
            float vx = o[ht][0] * a0, vy = o[ht][1] * a0, vz = o[ht][2] * a0, vw2 = o[ht][3] * a0;
            #pragma unroll
            for (int j = 0; j < 3; j++) {
                vx += oS[j][lane][ht * 4 + 0] * aj[j];
                vy += oS[j][lane][ht * 4 + 1] * aj[j];
                vz += oS[j][lane][ht * 4 + 2] * aj[j];
                vw2 += oS[j][lane][ht * 4 + 3] * aj[j];
            }
            ov.x = vx * invl; ov.y = vy * invl; ov.z = vz * invl; ov.w = vw2 * invl;
            *(float4*)(out + ((size_t)(b * T_) + qrow) * H_ + ht * 16 + quad * 4) = ov;
        }
    }
}

extern "C" void kernel_launch(void* const* d_in, const int* in_sizes, int n_in,
                              void* d_out, int out_size, void* d_ws, size_t ws_size,
                              hipStream_t stream) {
    const float* x    = (const float*)d_in[0];
    const float* mask = (const float*)d_in[1];
    const float* Wq   = (const float*)d_in[2];
    const float* Wk   = (const float*)d_in[3];
    const float* Wv   = (const float*)d_in[4];
    float* out = (float*)d_out;

    unsigned short* qw = (unsigned short*)d_ws;            // bf16 [B,T,H]
    unsigned short* kw = qw + (size_t)BT_ * H_;            // bf16 [B,T,H]
    unsigned short* vw = kw + (size_t)BT_ * H_;            // bf16 [B,H,T]
    unsigned short* wt = vw + (size_t)BT_ * H_;            // bf16 [192][768]

    wprep<<<36, 256, 0, stream>>>(Wq, Wk, Wv, wt);
    qkv_kernel<<<BT_ / 16, 128, 0, stream>>>(x, wt, qw, kw, vw);
    attn_kernel<<<B_ * (T_ / 16), 256, 0, stream>>>(qw, kw, vw, mask, out);
}